// Round 7
// baseline (101.207 us; speedup 1.0000x reference)
//
#include <hip/hip_runtime.h>
#include <math.h>

#define N_ATOMS 4096
#define CUTOFF2 25.0f
#define NTILE   16               // i-tiles of 256 atoms
#define NJ      128              // j slices
#define JT      32               // j per slice
#define LOG2E   1.4426950408889634f
#define LN2     0.6931471805599453f

__device__ __forceinline__ float pow20f(float t) {
    float t2 = t * t;
    float t4 = t2 * t2;
    float t8 = t4 * t4;
    float t16 = t8 * t8;
    return t16 * t4;
}

// deterministic block reduction (256 threads); result broadcast to all threads
__device__ __forceinline__ float block_reduce(float v, float* red) {
    __syncthreads();   // red may be reused
    #pragma unroll
    for (int off = 32; off > 0; off >>= 1) v += __shfl_down(v, off, 64);
    if ((threadIdx.x & 63) == 0) red[threadIdx.x >> 6] = v;
    __syncthreads();
    return (red[0] + red[1]) + (red[2] + red[3]);
}

// SoA packed params:
//   q0 = {x, y, z, re_inv}
//   q1 = {c1b=beta*log2e, la, fe, Bof=B/fe}   (exp arg = fma(-x, c1b, c1b))
//   q2 = {c1a=alpha*log2e, ka, A, 0}
__global__ __launch_bounds__(256) void pack_kernel(
    const float* __restrict__ coords, const float* __restrict__ params,
    float4* __restrict__ q0g, float4* __restrict__ q1g, float4* __restrict__ q2g,
    int* __restrict__ ctrs)
{
    if (blockIdx.x == 0 && threadIdx.x < NTILE + 1) ctrs[threadIdx.x] = 0;
    const int a = blockIdx.x * 256 + threadIdx.x;
    const float* p = params + 22 * a;
    const float fe = p[1];
    q0g[a] = { coords[3*a], coords[3*a+1], coords[3*a+2], __builtin_amdgcn_rcpf(p[0]) };
    q1g[a] = { p[5] * LOG2E, p[9], fe, p[7] * __builtin_amdgcn_rcpf(fe) };
    q2g[a] = { p[4] * LOG2E, p[8], p[6], 0.0f };
}

// grid (16,128) x 256 threads. Thread owns i = bi*256+tid; j loop is wave-uniform
// -> j-side float4 loads become s_load (scalar pipe, K$-cached). No LDS, no
// barriers in hot loop. Tile-last block embeds its 256 atoms; global-last block
// does the final fixed-order sum.
__global__ __launch_bounds__(256) void eam_main(
    const float* __restrict__ params,
    const float4* __restrict__ q0g, const float4* __restrict__ q1g,
    const float4* __restrict__ q2g,
    float* __restrict__ rho_part,    // [N_ATOMS][NJ]
    float* __restrict__ e_part,      // [NTILE*NJ]
    float* __restrict__ F_part,      // [NTILE]
    int* __restrict__ ctrs,          // [NTILE] tile counters, [NTILE] = global
    float* __restrict__ out)
{
    __shared__ float red[4];
    __shared__ int sTileLast, sGlobLast;

    const int tid = threadIdx.x;
    const int bi  = blockIdx.x;      // 0..15
    const int s   = blockIdx.y;      // 0..127
    const int i   = bi * 256 + tid;
    const int jbase = s * JT;

    const float4 pi0 = q0g[i];
    const float4 pi1 = q1g[i];
    const float4 pi2 = q2g[i];
    const float xi = pi0.x, yi = pi0.y, zi = pi0.z, re_inv_i = pi0.w;
    const float c1b_i = pi1.x, la_i = pi1.y, fe_i = pi1.z, Bof_i = pi1.w;
    const float c1a_i = pi2.x, ka_i = pi2.y, A_i = pi2.z;

    float rho0 = 0.0f, rho1 = 0.0f, e = 0.0f;

    #pragma unroll 8
    for (int k = 0; k < JT; ++k) {
        const int j = jbase + k;                 // wave-uniform -> s_load
        const float4 q0 = q0g[j];
        const float4 q1 = q1g[j];
        const float dx = q0.x - xi;
        const float dy = q0.y - yi;
        const float dz = q0.z - zi;
        const float r2 = fmaf(dx, dx, fmaf(dy, dy, dz * dz));
        const float r  = __builtin_amdgcn_sqrtf(r2);
        const float x  = r * q0.w;
        const float ej = __builtin_amdgcn_exp2f(fmaf(-x, q1.x, q1.x));
        const float dj = __builtin_amdgcn_rcpf(1.0f + pow20f(x - q1.y));
        const float frj = q1.z * ej * dj;
        const float add = (j == i) ? 0.0f : frj;
        if (k & 1) rho1 += add; else rho0 += add;

        if (r2 <= CUTOFF2 && i < j) {            // each unordered pair once
            const float4 q2 = q2g[j];
            const float xr  = r * re_inv_i;
            const float ei  = __builtin_amdgcn_exp2f(fmaf(-xr, c1b_i, c1b_i));
            const float di  = __builtin_amdgcn_rcpf(1.0f + pow20f(xr - la_i));
            const float fri = fe_i * ei * di;
            const float ph_i = A_i * __builtin_amdgcn_exp2f(fmaf(-xr, c1a_i, c1a_i))
                                   * __builtin_amdgcn_rcpf(1.0f + pow20f(xr - ka_i))
                             - Bof_i * fri;
            const float ph_j = q2.z * __builtin_amdgcn_exp2f(fmaf(-x, q2.x, q2.x))
                                    * __builtin_amdgcn_rcpf(1.0f + pow20f(x - q2.y))
                             - q1.w * frj;
            // frj/fri*ph_i + fri/frj*ph_j = (frj^2*ph_i + fri^2*ph_j)/(fri*frj)
            e += 0.5f * fmaf(frj * frj, ph_i, fri * fri * ph_j)
                      * __builtin_amdgcn_rcpf(fri * frj);
        }
    }

    rho_part[(size_t)i * NJ + s] = rho0 + rho1;

    const float eb = block_reduce(e, red);
    if (tid == 0) e_part[bi * NJ + s] = eb;

    __syncthreads();
    if (tid == 0) {
        // release: rho slice + e partial visible before count
        int prev = __hip_atomic_fetch_add(&ctrs[bi], 1, __ATOMIC_ACQ_REL,
                                          __HIP_MEMORY_SCOPE_AGENT);
        sTileLast = (prev == NJ - 1);
    }
    __syncthreads();

    if (sTileLast) {   // all 128 slices of tile bi done: embed its 256 atoms
        const float4* rp = (const float4*)(rho_part + (size_t)i * NJ);
        float s0 = 0.0f, s1 = 0.0f, s2 = 0.0f, s3 = 0.0f;
        #pragma unroll
        for (int k = 0; k < NJ / 4; ++k) {
            const float4 v = rp[k];
            s0 += v.x; s1 += v.y; s2 += v.z; s3 += v.w;
        }
        const float rhoi = (s0 + s1) + (s2 + s3);

        const float* p = params + 22 * i;
        float F;
        if (rhoi < p[20]) {
            const float xn = rhoi / p[20] - 1.0f;
            F = p[10] + xn * (p[11] + xn * (p[12] + xn * p[13]));
        } else if (rhoi < p[21]) {
            const float xe = rhoi / p[2] - 1.0f;
            F = p[14] + xe * (p[15] + xe * (p[16] + xe * p[17]));
        } else {
            const float l2 = __builtin_amdgcn_logf(rhoi / p[3]);   // log2
            const float t  = __builtin_amdgcn_exp2f(p[18] * l2);
            const float lt = p[18] * l2 * LN2;                     // ln(t)
            F = p[19] * (1.0f - lt) * t;
        }

        const float Fb = block_reduce(F, red);
        if (tid == 0) F_part[bi] = Fb;

        __syncthreads();
        if (tid == 0) {
            int prev = __hip_atomic_fetch_add(&ctrs[NTILE], 1, __ATOMIC_ACQ_REL,
                                              __HIP_MEMORY_SCOPE_AGENT);
            sGlobLast = (prev == NTILE - 1);
        }
        __syncthreads();

        if (sGlobLast) {   // all tiles done: fixed-order final sum
            float acc = 0.0f;
            #pragma unroll
            for (int k = 0; k < NTILE * NJ / 256; ++k) acc += e_part[k * 256 + tid];
            if (tid < NTILE) acc += F_part[tid];
            const float tot = block_reduce(acc, red);
            if (tid == 0) out[0] = tot;
        }
    }
}

extern "C" void kernel_launch(void* const* d_in, const int* in_sizes, int n_in,
                              void* d_out, int out_size, void* d_ws, size_t ws_size,
                              hipStream_t stream) {
    const float* coords = (const float*)d_in[0];   // [4096][3]
    const float* params = (const float*)d_in[1];   // [4096][22]
    float* out = (float*)d_out;

    float4* q0g = (float4*)d_ws;                      // [4096]
    float4* q1g = q0g + N_ATOMS;
    float4* q2g = q1g + N_ATOMS;
    float*  rho_part = (float*)(q2g + N_ATOMS);       // [4096][128]
    float*  e_part   = rho_part + (size_t)N_ATOMS * NJ;  // [2048]
    float*  F_part   = e_part + NTILE * NJ;           // [16]
    int*    ctrs     = (int*)(F_part + NTILE);        // [17]

    pack_kernel<<<N_ATOMS / 256, 256, 0, stream>>>(coords, params, q0g, q1g, q2g, ctrs);
    dim3 grid(NTILE, NJ);
    eam_main<<<grid, 256, 0, stream>>>(params, q0g, q1g, q2g,
                                       rho_part, e_part, F_part, ctrs, out);
}

// Round 8
// 69.246 us; speedup vs baseline: 1.4615x; 1.4615x over previous
//
#include <hip/hip_runtime.h>
#include <math.h>

#define N_ATOMS 4096
#define CUTOFF2 25.0f
#define NTILE   16               // i-tiles of 256 atoms
#define NJ      128              // j slices per tile row
#define JT      32               // j atoms per slice
#define LOG2E   1.4426950408889634f
#define LN2     0.6931471805599453f

__device__ __forceinline__ float pow20f(float t) {
    float t2 = t * t;
    float t4 = t2 * t2;
    float t8 = t4 * t4;
    float t16 = t8 * t8;
    return t16 * t4;
}

// deterministic block reduction (256 threads); result broadcast via red[0..3]
__device__ __forceinline__ float block_reduce(float v, float* red) {
    __syncthreads();
    #pragma unroll
    for (int off = 32; off > 0; off >>= 1) v += __shfl_down(v, off, 64);
    if ((threadIdx.x & 63) == 0) red[threadIdx.x >> 6] = v;
    __syncthreads();
    return (red[0] + red[1]) + (red[2] + red[3]);
}

// packed row (16 floats): [x,y,z,re_inv | c0b,c1b,mla,fe | c0a,c1a,mka,A | Bof,0,0,0]
//  c1b = beta*log2e, c0b = -c1b*re_inv  -> exp arg  = fma(r, c0b, c1b)
//  mla = -lambda                        -> pow arg  = fma(r, re_inv, mla)
//  c1a/c0a likewise for alpha, mka = -kappa, Bof = B/fe
__global__ __launch_bounds__(256) void pack_kernel(
    const float* __restrict__ coords, const float* __restrict__ params,
    float* __restrict__ packed, int* __restrict__ ctrs)
{
    if (blockIdx.x == 0 && threadIdx.x < NTILE + 1) ctrs[threadIdx.x] = 0;
    const int a = blockIdx.x * 256 + threadIdx.x;
    const float* p = params + 22 * a;
    const float re_inv = __builtin_amdgcn_rcpf(p[0]);
    const float fe  = p[1];
    const float c1b = p[5] * LOG2E;
    const float c1a = p[4] * LOG2E;
    float4* dst = (float4*)(packed + 16 * a);
    dst[0] = { coords[3*a], coords[3*a+1], coords[3*a+2], re_inv };
    dst[1] = { -c1b * re_inv, c1b, -p[9], fe };
    dst[2] = { -c1a * re_inv, c1a, -p[8], p[6] };
    dst[3] = { p[7] * __builtin_amdgcn_rcpf(fe), 0.0f, 0.0f, 0.0f };
}

// MODE: 0 = below diagonal (rho only), 1 = diagonal (full), 2 = above (rho + phi, no i<j test)
template <int MODE>
__device__ __forceinline__ void inner_loop(
    const float* spp, int jbase, int i,
    float xi, float yi, float zi, float re_inv_i,
    float c0b_i, float c1b_i, float mla_i, float fe_i,
    float c0a_i, float c1a_i, float mka_i, float A_i, float Bof_i,
    float& rho0, float& rho1, float& e)
{
    #pragma unroll 8
    for (int k = 0; k < JT; ++k) {
        const float4 q0 = *(const float4*)&spp[k * 16];      // x,y,z,re_inv
        const float4 q1 = *(const float4*)&spp[k * 16 + 4];  // c0b,c1b,mla,fe
        const float dx = q0.x - xi;
        const float dy = q0.y - yi;
        const float dz = q0.z - zi;
        const float r2 = fmaf(dx, dx, fmaf(dy, dy, dz * dz));
        const float r  = __builtin_amdgcn_sqrtf(r2);
        const float ej = __builtin_amdgcn_exp2f(fmaf(r, q1.x, q1.y));
        const float dj = __builtin_amdgcn_rcpf(1.0f + pow20f(fmaf(r, q0.w, q1.z)));
        const float frj = q1.w * ej * dj;
        float add = frj;
        if (MODE == 1) add = (jbase + k == i) ? 0.0f : frj;
        if (k & 1) rho1 += add; else rho0 += add;

        if (MODE > 0) {
            const bool hit = (r2 <= CUTOFF2) && (MODE == 2 || i < jbase + k);
            if (hit) {
                const float4 q2 = *(const float4*)&spp[k * 16 + 8];   // c0a,c1a,mka,A
                const float Bof_j = spp[k * 16 + 12];
                const float ei  = __builtin_amdgcn_exp2f(fmaf(r, c0b_i, c1b_i));
                const float di  = __builtin_amdgcn_rcpf(1.0f + pow20f(fmaf(r, re_inv_i, mla_i)));
                const float fri = fe_i * ei * di;
                const float ph_i = A_i * __builtin_amdgcn_exp2f(fmaf(r, c0a_i, c1a_i))
                                       * __builtin_amdgcn_rcpf(1.0f + pow20f(fmaf(r, re_inv_i, mka_i)))
                                 - Bof_i * fri;
                const float ph_j = q2.w * __builtin_amdgcn_exp2f(fmaf(r, q2.x, q2.y))
                                        * __builtin_amdgcn_rcpf(1.0f + pow20f(fmaf(r, q0.w, q2.z)))
                                 - Bof_j * frj;
                // frj/fri*ph_i + fri/frj*ph_j = (frj^2*ph_i + fri^2*ph_j)/(fri*frj)
                e += 0.5f * fmaf(frj * frj, ph_i, fri * fri * ph_j)
                          * __builtin_amdgcn_rcpf(fri * frj);
            }
        }
    }
}

// grid (16,128) x 256 threads. Thread owns i; block stages JT=32 j-atoms in LDS.
// rho_part[s][i] coalesced. Tile-last block embeds its 256 atoms; global-last sums.
__global__ __launch_bounds__(256) void eam_pair(
    const float* __restrict__ params, const float* __restrict__ packed,
    float* __restrict__ rho_part,    // [NJ][N_ATOMS]
    float* __restrict__ e_part,      // [NTILE*NJ]
    float* __restrict__ F_part,      // [NTILE]
    int* __restrict__ ctrs,          // [NTILE] tile, [NTILE] global
    float* __restrict__ out)
{
    __shared__ float spp[JT * 16];   // 2 KB
    __shared__ float red[4];
    __shared__ int sTileLast, sGlobLast;

    const int tid = threadIdx.x;
    const int bi  = blockIdx.x;
    const int bj  = blockIdx.y;
    const int i   = bi * 256 + tid;
    const int jbase = bj * JT;

    if (tid < JT * 4) {   // stage 32 rows x 4 float4, linear b128 copy
        ((float4*)spp)[tid] = ((const float4*)(packed + (size_t)jbase * 16))[tid];
    }
    __syncthreads();

    const float4 pi0 = *(const float4*)(packed + 16 * i);
    const float4 pi1 = *(const float4*)(packed + 16 * i + 4);
    const float4 pi2 = *(const float4*)(packed + 16 * i + 8);
    const float Bof_i = packed[16 * i + 12];

    float rho0 = 0.0f, rho1 = 0.0f, e = 0.0f;

    const int lo = bi * 256;
    if (jbase + JT <= lo) {
        inner_loop<0>(spp, jbase, i, pi0.x, pi0.y, pi0.z, pi0.w,
                      pi1.x, pi1.y, pi1.z, pi1.w, pi2.x, pi2.y, pi2.z, pi2.w,
                      Bof_i, rho0, rho1, e);
    } else if (jbase >= lo + 256) {
        inner_loop<2>(spp, jbase, i, pi0.x, pi0.y, pi0.z, pi0.w,
                      pi1.x, pi1.y, pi1.z, pi1.w, pi2.x, pi2.y, pi2.z, pi2.w,
                      Bof_i, rho0, rho1, e);
    } else {
        inner_loop<1>(spp, jbase, i, pi0.x, pi0.y, pi0.z, pi0.w,
                      pi1.x, pi1.y, pi1.z, pi1.w, pi2.x, pi2.y, pi2.z, pi2.w,
                      Bof_i, rho0, rho1, e);
    }

    rho_part[(size_t)bj * N_ATOMS + i] = rho0 + rho1;

    const float eb = block_reduce(e, red);
    if (tid == 0) e_part[bi * NJ + bj] = eb;

    __syncthreads();
    if (tid == 0) {
        int prev = __hip_atomic_fetch_add(&ctrs[bi], 1, __ATOMIC_ACQ_REL,
                                          __HIP_MEMORY_SCOPE_AGENT);
        sTileLast = (prev == NJ - 1);
    }
    __syncthreads();

    if (sTileLast) {   // all 128 slices of tile bi done -> embed its 256 atoms
        float s0 = 0.0f, s1 = 0.0f, s2 = 0.0f, s3 = 0.0f;
        #pragma unroll 8
        for (int s = 0; s < NJ; s += 4) {   // coalesced across threads per s
            s0 += rho_part[(size_t)(s + 0) * N_ATOMS + i];
            s1 += rho_part[(size_t)(s + 1) * N_ATOMS + i];
            s2 += rho_part[(size_t)(s + 2) * N_ATOMS + i];
            s3 += rho_part[(size_t)(s + 3) * N_ATOMS + i];
        }
        const float rhoi = (s0 + s1) + (s2 + s3);

        const float* p = params + 22 * i;
        float F;
        if (rhoi < p[20]) {
            const float xn = rhoi / p[20] - 1.0f;
            F = p[10] + xn * (p[11] + xn * (p[12] + xn * p[13]));
        } else if (rhoi < p[21]) {
            const float xe = rhoi / p[2] - 1.0f;
            F = p[14] + xe * (p[15] + xe * (p[16] + xe * p[17]));
        } else {
            const float l2 = __builtin_amdgcn_logf(rhoi / p[3]);   // log2
            const float t  = __builtin_amdgcn_exp2f(p[18] * l2);
            const float lt = p[18] * l2 * LN2;                     // ln
            F = p[19] * (1.0f - lt) * t;
        }

        const float Fb = block_reduce(F, red);
        if (tid == 0) F_part[bi] = Fb;

        __syncthreads();
        if (tid == 0) {
            int prev = __hip_atomic_fetch_add(&ctrs[NTILE], 1, __ATOMIC_ACQ_REL,
                                              __HIP_MEMORY_SCOPE_AGENT);
            sGlobLast = (prev == NTILE - 1);
        }
        __syncthreads();

        if (sGlobLast) {   // all tiles embedded: fixed-order final sum
            float acc = 0.0f;
            #pragma unroll
            for (int k = 0; k < NTILE * NJ / 256; ++k) acc += e_part[k * 256 + tid];
            if (tid < NTILE) acc += F_part[tid];
            const float tot = block_reduce(acc, red);
            if (tid == 0) out[0] = tot;
        }
    }
}

extern "C" void kernel_launch(void* const* d_in, const int* in_sizes, int n_in,
                              void* d_out, int out_size, void* d_ws, size_t ws_size,
                              hipStream_t stream) {
    const float* coords = (const float*)d_in[0];   // [4096][3]
    const float* params = (const float*)d_in[1];   // [4096][22]
    float* out = (float*)d_out;

    float* packed   = (float*)d_ws;                          // [4096][16]
    float* rho_part = packed + (size_t)N_ATOMS * 16;         // [128][4096]
    float* e_part   = rho_part + (size_t)NJ * N_ATOMS;       // [2048]
    float* F_part   = e_part + NTILE * NJ;                   // [16]
    int*   ctrs     = (int*)(F_part + NTILE);                // [17]

    pack_kernel<<<N_ATOMS / 256, 256, 0, stream>>>(coords, params, packed, ctrs);
    dim3 grid(NTILE, NJ);
    eam_pair<<<grid, 256, 0, stream>>>(params, packed, rho_part, e_part,
                                       F_part, ctrs, out);
}

// Round 9
// 29.109 us; speedup vs baseline: 3.4768x; 2.3789x over previous
//
#include <hip/hip_runtime.h>
#include <math.h>

#define N_ATOMS 4096
#define CUTOFF2 25.0f
#define NTILE   16               // i-tiles of 256
#define NJ      128              // j slices
#define JT      32               // j atoms per slice
#define LOG2E   1.4426950408889634f
#define LN2     0.6931471805599453f

typedef float v2f __attribute__((ext_vector_type(2)));

__device__ __forceinline__ float pow20f(float t) {
    float t2 = t * t, t4 = t2 * t2, t8 = t4 * t4, t16 = t8 * t8;
    return t16 * t4;
}
__device__ __forceinline__ v2f pow20v(v2f t) {
    v2f t2 = t * t, t4 = t2 * t2, t8 = t4 * t4, t16 = t8 * t8;
    return t16 * t4;
}

// deterministic block reduction (256 threads); result broadcast via red[0..3]
__device__ __forceinline__ float block_reduce(float v, float* red) {
    __syncthreads();
    #pragma unroll
    for (int off = 32; off > 0; off >>= 1) v += __shfl_down(v, off, 64);
    if ((threadIdx.x & 63) == 0) red[threadIdx.x >> 6] = v;
    __syncthreads();
    return (red[0] + red[1]) + (red[2] + red[3]);
}

// Per-atom phi rows apk[a][16]:
//  row0: x,y,z,rei   row1: c0b, c1b'(=b*log2e+log2 fe), mla, 0
//  row2: c0a, c1a, mka, A   row3: Bof(=B/fe), 0,0,0
//  => f_r(r) = 2^(c0b*r + c1b') * rcp(1 + pow20(rei*r + mla))   (fe folded in)
// Pair-interleaved rho rows rpk[p][16] for atoms (2p,2p+1):
//  [x0,x1,y0,y1 | z0,z1,rei0,rei1 | c0b0,c0b1,c1b0,c1b1 | mla0,mla1,0,0]
__global__ __launch_bounds__(256) void pack_kernel(
    const float* __restrict__ coords, const float* __restrict__ params,
    float* __restrict__ apk, float* __restrict__ rpk)
{
    const int a = blockIdx.x * 256 + threadIdx.x;
    const float* p = params + 22 * a;
    const float x = coords[3*a], y = coords[3*a+1], z = coords[3*a+2];
    const float rei = __builtin_amdgcn_rcpf(p[0]);
    const float bl2 = p[5] * LOG2E;
    const float al2 = p[4] * LOG2E;
    const float c0b = -bl2 * rei;
    const float c1b = bl2 + __builtin_amdgcn_logf(p[1]);   // + log2(fe)
    const float c0a = -al2 * rei;

    float4* ad = (float4*)(apk + 16 * a);
    ad[0] = { x, y, z, rei };
    ad[1] = { c0b, c1b, -p[9], 0.0f };
    ad[2] = { c0a, al2, -p[8], p[6] };
    ad[3] = { p[7] * __builtin_amdgcn_rcpf(p[1]), 0.0f, 0.0f, 0.0f };

    float* rd = rpk + 16 * (a >> 1) + (a & 1);
    rd[0]  = x;   rd[2]  = y;   rd[4]  = z;   rd[6] = rei;
    rd[8]  = c0b; rd[10] = c1b; rd[12] = -p[9]; rd[14] = 0.0f;
}

// K2: rho + hit bitmask. grid (16,128) x 256. Thread owns i; slice = 32 j (16 pairs).
// Packed v2f math -> v_pk_*; no phi branch, no reductions, no atomics.
__global__ __launch_bounds__(256) void eam_rho(
    const float* __restrict__ rpk, const float* __restrict__ apk,
    float* __restrict__ rho_part,    // [NJ][N_ATOMS]
    unsigned int* __restrict__ masks) // [NJ][N_ATOMS]
{
    __shared__ float4 sp4[JT * 4 / 2 * 2];   // 64 float4 = 1 KB (16 pairs x 4)

    const int tid = threadIdx.x;
    const int bi  = blockIdx.x;
    const int s   = blockIdx.y;
    const int i   = bi * 256 + tid;
    const int jbase = s * JT;

    if (tid < 64) sp4[tid] = ((const float4*)rpk)[s * 64 + tid];
    __syncthreads();

    const float4 a0 = *(const float4*)(apk + 16 * i);   // x,y,z,rei
    const float4 a1 = *(const float4*)(apk + 16 * i + 4); // c0b,c1b,mla,0
    const v2f xi2 = { a0.x, a0.x };
    const v2f yi2 = { a0.y, a0.y };
    const v2f zi2 = { a0.z, a0.z };

    v2f rho2 = { 0.0f, 0.0f };
    unsigned int mask = 0;

    #pragma unroll 4
    for (int k = 0; k < JT / 2; ++k) {
        const float4 f0 = sp4[k * 4 + 0];   // x0,x1,y0,y1
        const float4 f1 = sp4[k * 4 + 1];   // z0,z1,rei0,rei1
        const float4 f2 = sp4[k * 4 + 2];   // c0b0,c0b1,c1b0,c1b1
        const float4 f3 = sp4[k * 4 + 3];   // mla0,mla1,-,-
        const v2f x01 = { f0.x, f0.y }, y01 = { f0.z, f0.w };
        const v2f z01 = { f1.x, f1.y }, rei01 = { f1.z, f1.w };
        const v2f c0b01 = { f2.x, f2.y }, c1b01 = { f2.z, f2.w };
        const v2f mla01 = { f3.x, f3.y };

        const v2f dx = x01 - xi2;
        const v2f dy = y01 - yi2;
        const v2f dz = z01 - zi2;
        const v2f r2v = dx * dx + dy * dy + dz * dz;
        const v2f rv = { __builtin_amdgcn_sqrtf(r2v.x), __builtin_amdgcn_sqrtf(r2v.y) };
        const v2f ea = rv * c0b01 + c1b01;
        const v2f ev = { __builtin_amdgcn_exp2f(ea.x), __builtin_amdgcn_exp2f(ea.y) };
        const v2f pa = rv * rei01 + mla01;
        const v2f den = pow20v(pa) + 1.0f;
        const v2f dv = { __builtin_amdgcn_rcpf(den.x), __builtin_amdgcn_rcpf(den.y) };
        rho2 += ev * dv;

        const int j0 = jbase + 2 * k;
        if ((r2v.x <= CUTOFF2) & (j0 > i))     mask |= (1u << (2 * k));
        if ((r2v.y <= CUTOFF2) & (j0 + 1 > i)) mask |= (1u << (2 * k + 1));
    }

    float rho = rho2.x + rho2.y;
    if (i >= jbase && i < jbase + JT) {   // remove self term (r=0)
        rho -= __builtin_amdgcn_exp2f(a1.y)
             * __builtin_amdgcn_rcpf(1.0f + pow20f(a1.z));
    }

    rho_part[(size_t)s * N_ATOMS + i] = rho;
    masks[(size_t)s * N_ATOMS + i] = mask;
}

// K3: phi over masked pairs + (s==0 blocks) embedding. grid (16,128) x 256.
__global__ __launch_bounds__(256) void eam_phi(
    const float* __restrict__ params, const float* __restrict__ apk,
    const float* __restrict__ rho_part, const unsigned int* __restrict__ masks,
    float* __restrict__ e_part,      // [NTILE*NJ]
    float* __restrict__ F_part)      // [NTILE]
{
    __shared__ float4 sp4[JT * 4];   // 2 KB: slice phi rows
    __shared__ float red[4];

    const int tid = threadIdx.x;
    const int bi  = blockIdx.x;
    const int s   = blockIdx.y;
    const int i   = bi * 256 + tid;

    if (tid < JT * 4) sp4[tid] = ((const float4*)apk)[s * JT * 4 + tid];
    __syncthreads();

    const float4 a0 = *(const float4*)(apk + 16 * i);
    const float4 a1 = *(const float4*)(apk + 16 * i + 4);
    const float4 a2 = *(const float4*)(apk + 16 * i + 8);
    const float Bof_i = apk[16 * i + 12];

    float e = 0.0f;
    unsigned int m = masks[(size_t)s * N_ATOMS + i];

    while (m) {
        const int k = __builtin_ctz(m);
        m &= m - 1;
        const float4 q0 = sp4[k * 4 + 0];   // x,y,z,rei
        const float4 q1 = sp4[k * 4 + 1];   // c0b,c1b,mla,0
        const float4 q2 = sp4[k * 4 + 2];   // c0a,c1a,mka,A
        const float Bof_j = sp4[k * 4 + 3].x;

        const float dx = q0.x - a0.x;
        const float dy = q0.y - a0.y;
        const float dz = q0.z - a0.z;
        const float r = __builtin_amdgcn_sqrtf(fmaf(dx, dx, fmaf(dy, dy, dz * dz)));

        const float fri = __builtin_amdgcn_exp2f(fmaf(r, a1.x, a1.y))
                        * __builtin_amdgcn_rcpf(1.0f + pow20f(fmaf(r, a0.w, a1.z)));
        const float frj = __builtin_amdgcn_exp2f(fmaf(r, q1.x, q1.y))
                        * __builtin_amdgcn_rcpf(1.0f + pow20f(fmaf(r, q0.w, q1.z)));
        const float ph_i = a2.w * __builtin_amdgcn_exp2f(fmaf(r, a2.x, a2.y))
                                * __builtin_amdgcn_rcpf(1.0f + pow20f(fmaf(r, a0.w, a2.z)))
                         - Bof_i * fri;
        const float ph_j = q2.w * __builtin_amdgcn_exp2f(fmaf(r, q2.x, q2.y))
                                * __builtin_amdgcn_rcpf(1.0f + pow20f(fmaf(r, q0.w, q2.z)))
                         - Bof_j * frj;
        e += 0.5f * fmaf(frj * frj, ph_i, fri * fri * ph_j)
                  * __builtin_amdgcn_rcpf(fri * frj);
    }

    const float eb = block_reduce(e, red);
    if (tid == 0) e_part[bi * NJ + s] = eb;

    if (s == 0) {   // embedding for tile bi (rho_part complete: K2 finished)
        float s0 = 0.0f, s1 = 0.0f, s2 = 0.0f, s3 = 0.0f;
        #pragma unroll 8
        for (int t = 0; t < NJ; t += 4) {
            s0 += rho_part[(size_t)(t + 0) * N_ATOMS + i];
            s1 += rho_part[(size_t)(t + 1) * N_ATOMS + i];
            s2 += rho_part[(size_t)(t + 2) * N_ATOMS + i];
            s3 += rho_part[(size_t)(t + 3) * N_ATOMS + i];
        }
        const float rhoi = (s0 + s1) + (s2 + s3);

        const float* p = params + 22 * i;
        float F;
        if (rhoi < p[20]) {
            const float xn = rhoi / p[20] - 1.0f;
            F = p[10] + xn * (p[11] + xn * (p[12] + xn * p[13]));
        } else if (rhoi < p[21]) {
            const float xe = rhoi / p[2] - 1.0f;
            F = p[14] + xe * (p[15] + xe * (p[16] + xe * p[17]));
        } else {
            const float l2 = __builtin_amdgcn_logf(rhoi / p[3]);
            const float t  = __builtin_amdgcn_exp2f(p[18] * l2);
            const float lt = p[18] * l2 * LN2;
            F = p[19] * (1.0f - lt) * t;
        }
        const float Fb = block_reduce(F, red);
        if (tid == 0) F_part[bi] = Fb;
    }
}

// K4: final fixed-order sum
__global__ __launch_bounds__(256) void eam_final(
    const float* __restrict__ e_part, const float* __restrict__ F_part,
    float* __restrict__ out)
{
    __shared__ float red[4];
    const int tid = threadIdx.x;
    float acc = 0.0f;
    #pragma unroll
    for (int k = 0; k < NTILE * NJ / 256; ++k) acc += e_part[k * 256 + tid];
    if (tid < NTILE) acc += F_part[tid];
    const float tot = block_reduce(acc, red);
    if (tid == 0) out[0] = tot;
}

extern "C" void kernel_launch(void* const* d_in, const int* in_sizes, int n_in,
                              void* d_out, int out_size, void* d_ws, size_t ws_size,
                              hipStream_t stream) {
    const float* coords = (const float*)d_in[0];   // [4096][3]
    const float* params = (const float*)d_in[1];   // [4096][22]
    float* out = (float*)d_out;

    float* apk      = (float*)d_ws;                          // [4096][16]
    float* rpk      = apk + (size_t)N_ATOMS * 16;            // [2048][16]
    float* rho_part = rpk + (size_t)N_ATOMS * 16;            // [128][4096]
    unsigned int* masks = (unsigned int*)(rho_part + (size_t)NJ * N_ATOMS); // [128][4096]
    float* e_part   = (float*)(masks + (size_t)NJ * N_ATOMS);   // [2048]
    float* F_part   = e_part + NTILE * NJ;                   // [16]

    pack_kernel<<<N_ATOMS / 256, 256, 0, stream>>>(coords, params, apk, rpk);
    dim3 grid(NTILE, NJ);
    eam_rho<<<grid, 256, 0, stream>>>(rpk, apk, rho_part, masks);
    eam_phi<<<grid, 256, 0, stream>>>(params, apk, rho_part, masks, e_part, F_part);
    eam_final<<<1, 256, 0, stream>>>(e_part, F_part, out);
}

// Round 10
// 25.034 us; speedup vs baseline: 4.0427x; 1.1628x over previous
//
#include <hip/hip_runtime.h>
#include <math.h>

#define N_ATOMS 4096
#define CUTOFF2 25.0f
#define NTILE   16               // i-tiles of 256
#define NJ      128              // j slices
#define JT      32               // j atoms per slice
#define LOG2E   1.4426950408889634f
#define LN2     0.6931471805599453f

typedef float v2f __attribute__((ext_vector_type(2)));

__device__ __forceinline__ float pow20f(float t) {
    float t2 = t * t, t4 = t2 * t2, t8 = t4 * t4, t16 = t8 * t8;
    return t16 * t4;
}
__device__ __forceinline__ v2f pow20v(v2f t) {
    v2f t2 = t * t, t4 = t2 * t2, t8 = t4 * t4, t16 = t8 * t8;
    return t16 * t4;
}

// deterministic block reduction (256 threads); result broadcast via red[0..3]
__device__ __forceinline__ float block_reduce(float v, float* red) {
    __syncthreads();
    #pragma unroll
    for (int off = 32; off > 0; off >>= 1) v += __shfl_down(v, off, 64);
    if ((threadIdx.x & 63) == 0) red[threadIdx.x >> 6] = v;
    __syncthreads();
    return (red[0] + red[1]) + (red[2] + red[3]);
}

// K1: rho + phi fused. grid (16,128) x 256. Thread owns i = bi*256+tid.
// Slice (32 j) constants packed in-block to LDS; rho via packed v2f math over
// 16 j-pairs recording a hit bitmask; phi via ctz loop over set bits only.
__global__ __launch_bounds__(256) void eam_main(
    const float* __restrict__ coords, const float* __restrict__ params,
    float* __restrict__ rho_part,    // [NJ][N_ATOMS]
    float* __restrict__ e_part)      // [NTILE*NJ]
{
    // srho: 16 pairs x [x0,x1,y0,y1 | z0,z1,rei0,rei1 | c0b0,c0b1,c1b0,c1b1 | mla0,mla1,-,-]
    __shared__ float srho[16 * 16];          // 1 KB
    // sphi: 32 atoms x [x,y,z,rei | c0b,c1bp,mla,0 | c0a,c1a,mka,A | Bof,-,-,-]
    __shared__ float sphi[JT * 16];          // 2 KB
    __shared__ float red[4];

    const int tid = threadIdx.x;
    const int bi  = blockIdx.x;
    const int s   = blockIdx.y;
    const int i   = bi * 256 + tid;
    const int jbase = s * JT;

    if (tid < JT) {   // pack slice atom jbase+tid into LDS
        const int j = jbase + tid;
        const float* p = params + 22 * j;
        const float x = coords[3*j], y = coords[3*j+1], z = coords[3*j+2];
        const float rei  = __builtin_amdgcn_rcpf(p[0]);
        const float bl2  = p[5] * LOG2E;
        const float al2  = p[4] * LOG2E;
        const float c0b  = -bl2 * rei;
        const float c1bp = bl2 + __builtin_amdgcn_logf(p[1]);   // log2(fe) folded
        const float c0a  = -al2 * rei;
        const float mla  = -p[9];

        float* ph = sphi + 16 * tid;
        ph[0] = x;    ph[1] = y;    ph[2]  = z;     ph[3]  = rei;
        ph[4] = c0b;  ph[5] = c1bp; ph[6]  = mla;   ph[7]  = 0.0f;
        ph[8] = c0a;  ph[9] = al2;  ph[10] = -p[8]; ph[11] = p[6];
        ph[12] = p[7] * __builtin_amdgcn_rcpf(p[1]);            // Bof = B/fe

        float* rd = srho + 16 * (tid >> 1) + (tid & 1);
        rd[0] = x;   rd[2]  = y;    rd[4]  = z;   rd[6]  = rei;
        rd[8] = c0b; rd[10] = c1bp; rd[12] = mla;
    }

    // i-side constants (per-thread, from params; L2-resident broadcast-ish)
    const float* pi = params + 22 * i;
    const float xi = coords[3*i], yi = coords[3*i+1], zi = coords[3*i+2];
    const float rei_i  = __builtin_amdgcn_rcpf(pi[0]);
    const float bl2_i  = pi[5] * LOG2E;
    const float al2_i  = pi[4] * LOG2E;
    const float c0b_i  = -bl2_i * rei_i;
    const float c1bp_i = bl2_i + __builtin_amdgcn_logf(pi[1]);
    const float c0a_i  = -al2_i * rei_i;
    const float mla_i  = -pi[9];
    const float mka_i  = -pi[8];
    const float A_i    = pi[6];
    const float Bof_i  = pi[7] * __builtin_amdgcn_rcpf(pi[1]);

    __syncthreads();

    const v2f xi2 = { xi, xi }, yi2 = { yi, yi }, zi2 = { zi, zi };
    v2f rho2 = { 0.0f, 0.0f };
    unsigned int mask = 0;

    const float4* sp4 = (const float4*)srho;
    #pragma unroll 4
    for (int k = 0; k < JT / 2; ++k) {
        const float4 f0 = sp4[k * 4 + 0];   // x0,x1,y0,y1
        const float4 f1 = sp4[k * 4 + 1];   // z0,z1,rei0,rei1
        const float4 f2 = sp4[k * 4 + 2];   // c0b0,c0b1,c1b0,c1b1
        const float4 f3 = sp4[k * 4 + 3];   // mla0,mla1,-,-
        const v2f x01 = { f0.x, f0.y }, y01 = { f0.z, f0.w };
        const v2f z01 = { f1.x, f1.y }, rei01 = { f1.z, f1.w };
        const v2f c0b01 = { f2.x, f2.y }, c1b01 = { f2.z, f2.w };
        const v2f mla01 = { f3.x, f3.y };

        const v2f dx = x01 - xi2;
        const v2f dy = y01 - yi2;
        const v2f dz = z01 - zi2;
        const v2f r2v = dx * dx + dy * dy + dz * dz;
        const v2f rv = { __builtin_amdgcn_sqrtf(r2v.x), __builtin_amdgcn_sqrtf(r2v.y) };
        const v2f ea = rv * c0b01 + c1b01;
        const v2f ev = { __builtin_amdgcn_exp2f(ea.x), __builtin_amdgcn_exp2f(ea.y) };
        const v2f pa = rv * rei01 + mla01;
        const v2f den = pow20v(pa) + 1.0f;
        const v2f dv = { __builtin_amdgcn_rcpf(den.x), __builtin_amdgcn_rcpf(den.y) };
        rho2 += ev * dv;

        if (r2v.x <= CUTOFF2) mask |= (1u << (2 * k));
        if (r2v.y <= CUTOFF2) mask |= (1u << (2 * k + 1));
    }

    float rho = rho2.x + rho2.y;
    if (i >= jbase && i < jbase + JT) {   // remove self term (r=0)
        rho -= __builtin_amdgcn_exp2f(c1bp_i)
             * __builtin_amdgcn_rcpf(1.0f + pow20f(mla_i));
    }
    rho_part[(size_t)s * N_ATOMS + i] = rho;

    // phi over set bits with j > i only (pair counted once)
    {
        const int t = i - jbase;   // bits k <= t excluded
        unsigned int allowed = 0xFFFFFFFFu;
        if (t >= 31)     allowed = 0u;
        else if (t >= 0) allowed = ~((2u << t) - 1u);
        mask &= allowed;
    }

    float e = 0.0f;
    while (mask) {
        const int k = __builtin_ctz(mask);
        mask &= mask - 1;
        const float4 q0 = *(const float4*)&sphi[k * 16];       // x,y,z,rei
        const float4 q1 = *(const float4*)&sphi[k * 16 + 4];   // c0b,c1bp,mla,0
        const float4 q2 = *(const float4*)&sphi[k * 16 + 8];   // c0a,c1a,mka,A
        const float Bof_j = sphi[k * 16 + 12];

        const float dx = q0.x - xi;
        const float dy = q0.y - yi;
        const float dz = q0.z - zi;
        const float r = __builtin_amdgcn_sqrtf(fmaf(dx, dx, fmaf(dy, dy, dz * dz)));

        const float fri = __builtin_amdgcn_exp2f(fmaf(r, c0b_i, c1bp_i))
                        * __builtin_amdgcn_rcpf(1.0f + pow20f(fmaf(r, rei_i, mla_i)));
        const float frj = __builtin_amdgcn_exp2f(fmaf(r, q1.x, q1.y))
                        * __builtin_amdgcn_rcpf(1.0f + pow20f(fmaf(r, q0.w, q1.z)));
        const float ph_i = A_i * __builtin_amdgcn_exp2f(fmaf(r, c0a_i, al2_i))
                               * __builtin_amdgcn_rcpf(1.0f + pow20f(fmaf(r, rei_i, mka_i)))
                         - Bof_i * fri;
        const float ph_j = q2.w * __builtin_amdgcn_exp2f(fmaf(r, q2.x, q2.y))
                                * __builtin_amdgcn_rcpf(1.0f + pow20f(fmaf(r, q0.w, q2.z)))
                         - Bof_j * frj;
        // frj/fri*ph_i + fri/frj*ph_j = (frj^2*ph_i + fri^2*ph_j)/(fri*frj)
        e += 0.5f * fmaf(frj * frj, ph_i, fri * fri * ph_j)
                  * __builtin_amdgcn_rcpf(fri * frj);
    }

    const float eb = block_reduce(e, red);
    if (tid == 0) e_part[bi * NJ + s] = eb;
}

// K2: embed + per-tile e reduction. 16 blocks x 256 threads.
__global__ __launch_bounds__(256) void eam_embed(
    const float* __restrict__ params,
    const float* __restrict__ rho_part, const float* __restrict__ e_part,
    float* __restrict__ tile_sum)    // [NTILE]
{
    __shared__ float red[4];
    const int tid = threadIdx.x;
    const int bi  = blockIdx.x;
    const int i   = bi * 256 + tid;

    float s0 = 0.0f, s1 = 0.0f, s2 = 0.0f, s3 = 0.0f;
    #pragma unroll 8
    for (int t = 0; t < NJ; t += 4) {   // coalesced per slice
        s0 += rho_part[(size_t)(t + 0) * N_ATOMS + i];
        s1 += rho_part[(size_t)(t + 1) * N_ATOMS + i];
        s2 += rho_part[(size_t)(t + 2) * N_ATOMS + i];
        s3 += rho_part[(size_t)(t + 3) * N_ATOMS + i];
    }
    const float rhoi = (s0 + s1) + (s2 + s3);

    const float* p = params + 22 * i;
    float F;
    if (rhoi < p[20]) {
        const float xn = rhoi / p[20] - 1.0f;
        F = p[10] + xn * (p[11] + xn * (p[12] + xn * p[13]));
    } else if (rhoi < p[21]) {
        const float xe = rhoi / p[2] - 1.0f;
        F = p[14] + xe * (p[15] + xe * (p[16] + xe * p[17]));
    } else {
        const float l2 = __builtin_amdgcn_logf(rhoi / p[3]);   // log2
        const float t  = __builtin_amdgcn_exp2f(p[18] * l2);
        const float lt = p[18] * l2 * LN2;                     // ln
        F = p[19] * (1.0f - lt) * t;
    }

    float acc = F + ((tid < NJ) ? e_part[bi * NJ + tid] : 0.0f);
    const float tot = block_reduce(acc, red);
    if (tid == 0) tile_sum[bi] = tot;
}

// K3: final fixed-order sum of 16 tile sums (single wave)
__global__ __launch_bounds__(64) void eam_final(
    const float* __restrict__ tile_sum, float* __restrict__ out)
{
    const int tid = threadIdx.x;
    float acc = (tid < NTILE) ? tile_sum[tid] : 0.0f;
    #pragma unroll
    for (int off = 8; off > 0; off >>= 1) acc += __shfl_down(acc, off, 64);
    if (tid == 0) out[0] = acc;
}

extern "C" void kernel_launch(void* const* d_in, const int* in_sizes, int n_in,
                              void* d_out, int out_size, void* d_ws, size_t ws_size,
                              hipStream_t stream) {
    const float* coords = (const float*)d_in[0];   // [4096][3]
    const float* params = (const float*)d_in[1];   // [4096][22]
    float* out = (float*)d_out;

    float* rho_part = (float*)d_ws;                          // [128][4096]
    float* e_part   = rho_part + (size_t)NJ * N_ATOMS;       // [2048]
    float* tile_sum = e_part + NTILE * NJ;                   // [16]

    dim3 grid(NTILE, NJ);
    eam_main<<<grid, 256, 0, stream>>>(coords, params, rho_part, e_part);
    eam_embed<<<NTILE, 256, 0, stream>>>(params, rho_part, e_part, tile_sum);
    eam_final<<<1, 64, 0, stream>>>(tile_sum, out);
}